// Round 1
// baseline (1512.345 us; speedup 1.0000x reference)
//
#include <hip/hip_runtime.h>
#include <math.h>

// Problem constants
// B=4, N=256, D=512, H=8, HD=64, L=3, K_SPARSE=25, EPS=1e-5

// ---------------------------------------------------------------------------
// Generic GEMM: C[M,N] = act(A[M,K] @ W[K,N] + bias) with f64 accumulation.
// M,N multiples of 64; K multiple of 16. 256 threads, 64x64 tile, 4x4/thread.
// ---------------------------------------------------------------------------
__global__ __launch_bounds__(256) void gemm_f64acc(
    const float* __restrict__ A, const float* __restrict__ W,
    const float* __restrict__ bias, float* __restrict__ C,
    int M, int N, int K, int relu)
{
    __shared__ float As[16][64];   // [k][m]
    __shared__ float Ws[16][64];   // [k][n]
    const int tid = threadIdx.x;
    const int tx = tid & 15, ty = tid >> 4;
    const int bm = blockIdx.y * 64, bn = blockIdx.x * 64;
    double acc[4][4] = {};
    for (int k0 = 0; k0 < K; k0 += 16) {
        {   // A tile 64 rows x 16 k, store transposed
            int r  = tid >> 2;
            int c4 = (tid & 3) << 2;
            const float4 v = *(const float4*)(A + (size_t)(bm + r) * K + k0 + c4);
            As[c4 + 0][r] = v.x; As[c4 + 1][r] = v.y;
            As[c4 + 2][r] = v.z; As[c4 + 3][r] = v.w;
        }
        {   // W tile 16 k x 64 cols
            int kr = tid >> 4;
            int c4 = (tid & 15) << 2;
            *(float4*)(&Ws[kr][c4]) = *(const float4*)(W + (size_t)(k0 + kr) * N + bn + c4);
        }
        __syncthreads();
        #pragma unroll
        for (int kk = 0; kk < 16; ++kk) {
            float a0 = As[kk][ty * 4 + 0], a1 = As[kk][ty * 4 + 1];
            float a2 = As[kk][ty * 4 + 2], a3 = As[kk][ty * 4 + 3];
            float w0 = Ws[kk][tx * 4 + 0], w1 = Ws[kk][tx * 4 + 1];
            float w2 = Ws[kk][tx * 4 + 2], w3 = Ws[kk][tx * 4 + 3];
            double da[4] = {a0, a1, a2, a3};
            double dw[4] = {w0, w1, w2, w3};
            #pragma unroll
            for (int i = 0; i < 4; ++i)
                #pragma unroll
                for (int j = 0; j < 4; ++j)
                    acc[i][j] += da[i] * dw[j];
        }
        __syncthreads();
    }
    #pragma unroll
    for (int i = 0; i < 4; ++i) {
        int row = bm + ty * 4 + i;
        #pragma unroll
        for (int j = 0; j < 4; ++j) {
            int col = bn + tx * 4 + j;
            double v = acc[i][j];
            if (bias) v += (double)bias[col];
            float f = (float)v;
            if (relu) f = fmaxf(f, 0.f);
            C[(size_t)row * N + col] = f;
        }
    }
}

// ---------------------------------------------------------------------------
// Fused MHA core (per level): out[b,i,h*64+d] = softmax(QK^T * 0.125) V
// qkv layout [B][n][1536] (q | k | v). One wave per (b,h,q-row). HD=64=wave.
// grid: (n/4, H, B), block 256 (4 waves).
// ---------------------------------------------------------------------------
__global__ __launch_bounds__(256) void attn_kernel(
    const float* __restrict__ qkv, float* __restrict__ out, int n)
{
    const int lane = threadIdx.x & 63;
    const int wave = threadIdx.x >> 6;
    const int qi = blockIdx.x * 4 + wave;
    const int h = blockIdx.y, b = blockIdx.z;
    const size_t base = (size_t)b * n * 1536;
    const int nt = n >> 6;  // scores per lane (1,2,4)

    float q = qkv[base + (size_t)qi * 1536 + h * 64 + lane];
    float s[4];
    for (int j = 0; j < n; ++j) {
        float prod = q * qkv[base + (size_t)j * 1536 + 512 + h * 64 + lane];
        #pragma unroll
        for (int off = 32; off; off >>= 1) prod += __shfl_xor(prod, off);
        if ((j & 63) == lane) s[j >> 6] = prod * 0.125f;
    }
    // softmax (max in f32, sum in f64)
    float m = -INFINITY;
    for (int t = 0; t < nt; ++t) m = fmaxf(m, s[t]);
    #pragma unroll
    for (int off = 32; off; off >>= 1) m = fmaxf(m, __shfl_xor(m, off));
    float p[4];
    double sum = 0.0;
    for (int t = 0; t < nt; ++t) { p[t] = expf(s[t] - m); sum += (double)p[t]; }
    #pragma unroll
    for (int off = 32; off; off >>= 1) sum += __shfl_xor(sum, off);
    const double inv = 1.0 / sum;

    double acc = 0.0;
    for (int j = 0; j < n; ++j) {
        float pj = __shfl(p[j >> 6], j & 63);
        acc += (double)pj * (double)qkv[base + (size_t)j * 1536 + 1024 + h * 64 + lane];
    }
    out[((size_t)(b * n + qi)) * 512 + h * 64 + lane] = (float)(acc * inv);
}

// ---------------------------------------------------------------------------
// Pairwise pooling: out[b,i,d] = 0.5*(in[b,2i,d]+in[b,2i+1,d]); m = out nodes
// ---------------------------------------------------------------------------
__global__ __launch_bounds__(256) void pool_kernel(
    const float* __restrict__ in, float* __restrict__ out, int m)
{
    int idx = blockIdx.x * 256 + threadIdx.x;
    int total = 4 * m * 512;
    if (idx >= total) return;
    int d = idx & 511;
    int rest = idx >> 9;       // b*m + i
    int i = rest % m, b = rest / m;
    size_t r0 = (size_t)(b * 2 * m + 2 * i) * 512 + d;
    out[idx] = 0.5f * (in[r0] + in[r0 + 512]);
}

// ---------------------------------------------------------------------------
// Concat upsampled levels: cat[b*256+i][0:512|512:1024|1024:1536]
// ---------------------------------------------------------------------------
__global__ __launch_bounds__(256) void concat_kernel(
    const float* __restrict__ l0, const float* __restrict__ l1,
    const float* __restrict__ l2, float* __restrict__ out)
{
    int idx = blockIdx.x * 256 + threadIdx.x;
    if (idx >= 1024 * 1536) return;
    int c = idx % 1536, r = idx / 1536;
    int b = r >> 8, i = r & 255;
    float v;
    if (c < 512)       v = l0[(size_t)r * 512 + c];
    else if (c < 1024) v = l1[(size_t)(b * 128 + (i >> 1)) * 512 + c - 512];
    else               v = l2[(size_t)(b * 64 + (i >> 2)) * 512 + c - 1024];
    out[idx] = v;
}

// ---------------------------------------------------------------------------
// LayerNorm over D=512, one wave per row, f64 stats, two-pass (mean then var)
// ---------------------------------------------------------------------------
__global__ __launch_bounds__(64) void ln_kernel(
    const float* __restrict__ X, const float* __restrict__ g,
    const float* __restrict__ bta, float* __restrict__ Y)
{
    const int row = blockIdx.x, lane = threadIdx.x;
    const float* x = X + (size_t)row * 512;
    float v[8];
    double sum = 0.0;
    #pragma unroll
    for (int t = 0; t < 8; ++t) { v[t] = x[t * 64 + lane]; sum += (double)v[t]; }
    #pragma unroll
    for (int off = 32; off; off >>= 1) sum += __shfl_xor(sum, off);
    const double mean = sum * (1.0 / 512.0);
    double ss = 0.0;
    #pragma unroll
    for (int t = 0; t < 8; ++t) { double d = (double)v[t] - mean; ss += d * d; }
    #pragma unroll
    for (int off = 32; off; off >>= 1) ss += __shfl_xor(ss, off);
    const double rstd = 1.0 / sqrt(ss * (1.0 / 512.0) + 1e-5);
    #pragma unroll
    for (int t = 0; t < 8; ++t) {
        int d = t * 64 + lane;
        Y[(size_t)row * 512 + d] =
            (float)(((double)v[t] - mean) * rstd) * g[d] + bta[d];
    }
}

// ---------------------------------------------------------------------------
// Edge scores: S[b,i,j] = sigmoid(sum_d relu(hi[b,i,d]+hj[b,j,d])*We2[d]+be2)
// diag forced to 0. grid: (256, 4)=(i,b); block 256 = 4 waves, wave per j.
// ---------------------------------------------------------------------------
__global__ __launch_bounds__(256) void scores_kernel(
    const float* __restrict__ hi, const float* __restrict__ hj,
    const float* __restrict__ We2, const float* __restrict__ be2,
    float* __restrict__ S)
{
    const int i = blockIdx.x, b = blockIdx.y;
    const int lane = threadIdx.x & 63, wave = threadIdx.x >> 6;
    __shared__ float hrow[512];
    __shared__ float w2[512];
    for (int t = threadIdx.x; t < 512; t += 256) {
        hrow[t] = hi[(size_t)(b * 256 + i) * 512 + t];
        w2[t] = We2[t];
    }
    __syncthreads();
    const double bb = (double)be2[0];
    for (int j = wave; j < 256; j += 4) {
        const float* hjp = hj + (size_t)(b * 256 + j) * 512;
        double acc = 0.0;
        #pragma unroll
        for (int t = 0; t < 8; ++t) {
            int d = t * 64 + lane;
            float pre = hrow[d] + hjp[d];
            acc += (double)fmaxf(pre, 0.f) * (double)w2[d];
        }
        #pragma unroll
        for (int off = 32; off; off >>= 1) acc += __shfl_xor(acc, off);
        if (lane == 0) {
            double z = acc + bb;
            float sc = (float)(1.0 / (1.0 + exp(-z)));
            if (j == i) sc = 0.f;
            S[(size_t)(b * 256 + i) * 256 + j] = sc;
        }
    }
}

// ---------------------------------------------------------------------------
// Top-k(25) one-hot per row of 256 (ties -> lower index, like lax.top_k).
// One wave per row; iterative argmax.
// ---------------------------------------------------------------------------
__global__ __launch_bounds__(64) void topk_kernel(
    const float* __restrict__ S, float* __restrict__ out)
{
    const int row = blockIdx.x;       // b*256+i
    const int lane = threadIdx.x;
    float v[4]; int sel[4] = {0, 0, 0, 0};
    #pragma unroll
    for (int t = 0; t < 4; ++t) v[t] = S[(size_t)row * 256 + t * 64 + lane];
    for (int it = 0; it < 25; ++it) {
        float bv = v[0]; int bi = lane;
        #pragma unroll
        for (int t = 1; t < 4; ++t) {
            int idx = t * 64 + lane;
            if (v[t] > bv) { bv = v[t]; bi = idx; }
        }
        #pragma unroll
        for (int off = 32; off; off >>= 1) {
            float ov = __shfl_xor(bv, off);
            int   oi = __shfl_xor(bi, off);
            if (ov > bv || (ov == bv && oi < bi)) { bv = ov; bi = oi; }
        }
        if ((bi & 63) == lane) { int t = bi >> 6; sel[t] = 1; v[t] = -INFINITY; }
    }
    #pragma unroll
    for (int t = 0; t < 4; ++t)
        out[(size_t)row * 256 + t * 64 + lane] = (float)sel[t];
}

// ---------------------------------------------------------------------------
extern "C" void kernel_launch(void* const* d_in, const int* in_sizes, int n_in,
                              void* d_out, int out_size, void* d_ws, size_t ws_size,
                              hipStream_t stream)
{
    const float* x      = (const float*)d_in[0];
    // d_in[1] = adjacency (unused by reference)
    const float* Wqkv   = (const float*)d_in[2];
    const float* bqkv   = (const float*)d_in[3];
    const float* Wo     = (const float*)d_in[4];
    const float* bo     = (const float*)d_in[5];
    const float* Wp1    = (const float*)d_in[6];
    const float* bp1    = (const float*)d_in[7];
    const float* Wp2    = (const float*)d_in[8];
    const float* bp2    = (const float*)d_in[9];
    const float* Wfuse  = (const float*)d_in[10];
    const float* bfuse  = (const float*)d_in[11];
    const float* ln_g   = (const float*)d_in[12];
    const float* ln_b   = (const float*)d_in[13];
    const float* We1    = (const float*)d_in[14];
    const float* be1    = (const float*)d_in[15];
    const float* We2    = (const float*)d_in[16];
    const float* be2    = (const float*)d_in[17];
    const float* Ws_qkv = (const float*)d_in[18];
    const float* bs_qkv = (const float*)d_in[19];
    const float* Ws_o   = (const float*)d_in[20];
    const float* bs_o   = (const float*)d_in[21];

    float* out_att    = (float*)d_out;               // 4*256*512
    float* out_sparse = out_att + 4 * 256 * 512;     // 4*256*256

    // workspace layout (floats)
    float* ws   = (float*)d_ws;
    float* qkvb = ws;                    // 1,572,864  (also reused as concat)
    float* attnb = qkvb + 1572864;       //   524,288  (pre-proj attn / p / preln)
    float* lvl0 = attnb + 524288;        //   524,288
    float* lvl1 = lvl0 + 524288;         //   262,144
    float* lvl2 = lvl1 + 262144;         //   131,072
    float* curb = lvl2 + 131072;         //   262,144
    float* phb  = curb + 262144;         //   262,144
    float* hier = phb + 262144;          //   524,288
    float* hib  = hier + 524288;         //   524,288
    float* hjb  = hib + 524288;          //   524,288
    float* scb  = hjb + 524288;          //   262,144
    // total 5,373,952 floats = 21.5 MB

    auto G = [&](const float* A, const float* W, const float* bias, float* C,
                 int M, int N, int K, int relu) {
        gemm_f64acc<<<dim3(N / 64, M / 64), 256, 0, stream>>>(A, W, bias, C, M, N, K, relu);
    };

    // ---- Level 0 (n=256) ----
    G(x, Wqkv, bqkv, qkvb, 1024, 1536, 512, 0);
    attn_kernel<<<dim3(64, 8, 4), 256, 0, stream>>>(qkvb, attnb, 256);
    G(attnb, Wo, bo, lvl0, 1024, 512, 512, 0);
    G(lvl0, Wp1, bp1, phb, 1024, 256, 512, 1);
    G(phb, Wp2, bp2, attnb, 1024, 512, 256, 0);                 // p -> attnb
    pool_kernel<<<(4 * 128 * 512 + 255) / 256, 256, 0, stream>>>(attnb, curb, 128);

    // ---- Level 1 (n=128) ----
    G(curb, Wqkv + 512 * 1536, bqkv + 1536, qkvb, 512, 1536, 512, 0);
    attn_kernel<<<dim3(32, 8, 4), 256, 0, stream>>>(qkvb, attnb, 128);
    G(attnb, Wo + 512 * 512, bo + 512, lvl1, 512, 512, 512, 0);
    G(lvl1, Wp1 + 512 * 256, bp1 + 256, phb, 512, 256, 512, 1);
    G(phb, Wp2 + 256 * 512, bp2 + 512, attnb, 512, 512, 256, 0);
    pool_kernel<<<(4 * 64 * 512 + 255) / 256, 256, 0, stream>>>(attnb, curb, 64);

    // ---- Level 2 (n=64) ----
    G(curb, Wqkv + 2 * 512 * 1536, bqkv + 2 * 1536, qkvb, 256, 1536, 512, 0);
    attn_kernel<<<dim3(16, 8, 4), 256, 0, stream>>>(qkvb, attnb, 64);
    G(attnb, Wo + 2 * 512 * 512, bo + 2 * 512, lvl2, 256, 512, 512, 0);

    // ---- Fuse + LN ----
    concat_kernel<<<(1024 * 1536 + 255) / 256, 256, 0, stream>>>(lvl0, lvl1, lvl2, qkvb);
    G(qkvb, Wfuse, bfuse, attnb, 1024, 512, 1536, 1);           // preln -> attnb
    ln_kernel<<<1024, 64, 0, stream>>>(attnb, ln_g, ln_b, hier);

    // ---- Sparse edge scoring + top-k ----
    G(hier, We1, nullptr, hib, 1024, 512, 512, 0);
    G(hier, We1 + 512 * 512, be1, hjb, 1024, 512, 512, 0);
    scores_kernel<<<dim3(256, 4), 256, 0, stream>>>(hib, hjb, We2, be2, scb);
    topk_kernel<<<1024, 64, 0, stream>>>(scb, out_sparse);

    // ---- Final MHA on hier ----
    G(hier, Ws_qkv, bs_qkv, qkvb, 1024, 1536, 512, 0);
    attn_kernel<<<dim3(64, 8, 4), 256, 0, stream>>>(qkvb, attnb, 256);
    G(attnb, Ws_o, bs_o, out_att, 1024, 512, 512, 0);
}

// Round 2
// 973.030 us; speedup vs baseline: 1.5543x; 1.5543x over previous
//
#include <hip/hip_runtime.h>
#include <math.h>

// Problem constants: B=4, N=256, D=512, H=8, HD=64, L=3, K_SPARSE=25, EPS=1e-5

// ---------------------------------------------------------------------------
// Generic GEMM: C[M,N] = act(A[M,K] @ W[K,N] + bias), ACC = double or float.
// M,N multiples of 64; K multiple of 16. 256 threads, 64x64 tile, 4x4/thread.
// ---------------------------------------------------------------------------
template <typename ACC>
__global__ __launch_bounds__(256) void gemm_t(
    const float* __restrict__ A, const float* __restrict__ W,
    const float* __restrict__ bias, float* __restrict__ C,
    int M, int N, int K, int relu)
{
    __shared__ float As[16][64];   // [k][m]
    __shared__ float Ws[16][64];   // [k][n]
    const int tid = threadIdx.x;
    const int tx = tid & 15, ty = tid >> 4;
    const int bm = blockIdx.y * 64, bn = blockIdx.x * 64;
    ACC acc[4][4] = {};
    for (int k0 = 0; k0 < K; k0 += 16) {
        {   // A tile 64 rows x 16 k, store transposed
            int r  = tid >> 2;
            int c4 = (tid & 3) << 2;
            const float4 v = *(const float4*)(A + (size_t)(bm + r) * K + k0 + c4);
            As[c4 + 0][r] = v.x; As[c4 + 1][r] = v.y;
            As[c4 + 2][r] = v.z; As[c4 + 3][r] = v.w;
        }
        {   // W tile 16 k x 64 cols
            int kr = tid >> 4;
            int c4 = (tid & 15) << 2;
            *(float4*)(&Ws[kr][c4]) = *(const float4*)(W + (size_t)(k0 + kr) * N + bn + c4);
        }
        __syncthreads();
        #pragma unroll
        for (int kk = 0; kk < 16; ++kk) {
            float a0 = As[kk][ty * 4 + 0], a1 = As[kk][ty * 4 + 1];
            float a2 = As[kk][ty * 4 + 2], a3 = As[kk][ty * 4 + 3];
            float w0 = Ws[kk][tx * 4 + 0], w1 = Ws[kk][tx * 4 + 1];
            float w2 = Ws[kk][tx * 4 + 2], w3 = Ws[kk][tx * 4 + 3];
            ACC da[4] = {(ACC)a0, (ACC)a1, (ACC)a2, (ACC)a3};
            ACC dw[4] = {(ACC)w0, (ACC)w1, (ACC)w2, (ACC)w3};
            #pragma unroll
            for (int i = 0; i < 4; ++i)
                #pragma unroll
                for (int j = 0; j < 4; ++j)
                    acc[i][j] += da[i] * dw[j];
        }
        __syncthreads();
    }
    #pragma unroll
    for (int i = 0; i < 4; ++i) {
        int row = bm + ty * 4 + i;
        #pragma unroll
        for (int j = 0; j < 4; ++j) {
            int col = bn + tx * 4 + j;
            ACC v = acc[i][j];
            if (bias) v += (ACC)bias[col];
            float f = (float)v;
            if (relu) f = fmaxf(f, 0.f);
            C[(size_t)row * N + col] = f;
        }
    }
}

// ---------------------------------------------------------------------------
// Fused MHA core: out[b,i,h*64+d] = softmax(QK^T * 0.125) V
// qkv layout [B][n][1536] (q | k | v). Block = (4 q-rows, h, b), 4 waves.
// K/V staged in LDS 64-row tiles; scores lane-parallel (lane jl = col j0+jl);
// softmax reduced once per row; PV via LDS-transposed P, f64 accumulation.
// ---------------------------------------------------------------------------
__global__ __launch_bounds__(256) void attn_fused(
    const float* __restrict__ qkv, float* __restrict__ out, int n)
{
    const int lane = threadIdx.x & 63;
    const int w    = threadIdx.x >> 6;
    const int h = blockIdx.y, b = blockIdx.z;
    const int qi = blockIdx.x * 4 + w;
    const int nt = n >> 6;                  // 64-col tiles (1, 2, or 4)
    const size_t base = (size_t)b * n * 1536;

    __shared__ float q_lds[4][64];
    __shared__ float kv_lds[64][65];
    __shared__ float p_lds[4][256];

    // stage Q rows (one per wave)
    q_lds[w][lane] = qkv[base + (size_t)qi * 1536 + h * 64 + lane];

    // ---- scores: S[qi][j] = (q . k_j) * 0.125 ----
    float s[4];
    for (int t = 0; t < nt; ++t) {
        const int j0 = t * 64;
        __syncthreads();
        {   // stage K tile rows j0..j0+63
            int r = threadIdx.x >> 2;
            int q4 = threadIdx.x & 3;
            const float* src = qkv + base + (size_t)(j0 + r) * 1536 + 512 + h * 64;
            #pragma unroll
            for (int u = 0; u < 4; ++u) {
                int c = u * 4 + q4;                    // float4 index 0..15
                float4 v = *(const float4*)(src + c * 4);
                kv_lds[r][c * 4 + 0] = v.x; kv_lds[r][c * 4 + 1] = v.y;
                kv_lds[r][c * 4 + 2] = v.z; kv_lds[r][c * 4 + 3] = v.w;
            }
        }
        __syncthreads();
        float a0 = 0.f, a1 = 0.f, a2 = 0.f, a3 = 0.f;
        #pragma unroll
        for (int d = 0; d < 64; d += 4) {
            a0 += q_lds[w][d + 0] * kv_lds[lane][d + 0];
            a1 += q_lds[w][d + 1] * kv_lds[lane][d + 1];
            a2 += q_lds[w][d + 2] * kv_lds[lane][d + 2];
            a3 += q_lds[w][d + 3] * kv_lds[lane][d + 3];
        }
        s[t] = ((a0 + a1) + (a2 + a3)) * 0.125f;
    }

    // ---- softmax over the row (register + wave reduce, once) ----
    float m = s[0];
    for (int t = 1; t < nt; ++t) m = fmaxf(m, s[t]);
    #pragma unroll
    for (int off = 32; off; off >>= 1) m = fmaxf(m, __shfl_xor(m, off));
    float p[4];
    double sum = 0.0;
    for (int t = 0; t < nt; ++t) { p[t] = expf(s[t] - m); sum += (double)p[t]; }
    #pragma unroll
    for (int off = 32; off; off >>= 1) sum += __shfl_xor(sum, off);
    const double inv = 1.0 / sum;
    for (int t = 0; t < nt; ++t) p_lds[w][t * 64 + lane] = p[t];

    // ---- PV: out[d=lane] = sum_j p_j * V[j][d], f64 accumulation ----
    double acc = 0.0;
    for (int t = 0; t < nt; ++t) {
        const int j0 = t * 64;
        __syncthreads();
        {   // stage V tile
            int r = threadIdx.x >> 2;
            int q4 = threadIdx.x & 3;
            const float* src = qkv + base + (size_t)(j0 + r) * 1536 + 1024 + h * 64;
            #pragma unroll
            for (int u = 0; u < 4; ++u) {
                int c = u * 4 + q4;
                float4 v = *(const float4*)(src + c * 4);
                kv_lds[r][c * 4 + 0] = v.x; kv_lds[r][c * 4 + 1] = v.y;
                kv_lds[r][c * 4 + 2] = v.z; kv_lds[r][c * 4 + 3] = v.w;
            }
        }
        __syncthreads();
        #pragma unroll 8
        for (int jl = 0; jl < 64; ++jl)
            acc += (double)p_lds[w][j0 + jl] * (double)kv_lds[jl][lane];
    }
    out[((size_t)(b * n + qi)) * 512 + h * 64 + lane] = (float)(acc * inv);
}

// ---------------------------------------------------------------------------
// Pairwise pooling: out[b,i,d] = 0.5*(in[b,2i,d]+in[b,2i+1,d]); m = out nodes
// ---------------------------------------------------------------------------
__global__ __launch_bounds__(256) void pool_kernel(
    const float* __restrict__ in, float* __restrict__ out, int m)
{
    int idx = blockIdx.x * 256 + threadIdx.x;
    int total = 4 * m * 512;
    if (idx >= total) return;
    int d = idx & 511;
    int rest = idx >> 9;       // b*m + i
    int i = rest % m, b = rest / m;
    size_t r0 = (size_t)(b * 2 * m + 2 * i) * 512 + d;
    out[idx] = 0.5f * (in[r0] + in[r0 + 512]);
}

// ---------------------------------------------------------------------------
// Concat upsampled levels: cat[b*256+i][0:512|512:1024|1024:1536]
// ---------------------------------------------------------------------------
__global__ __launch_bounds__(256) void concat_kernel(
    const float* __restrict__ l0, const float* __restrict__ l1,
    const float* __restrict__ l2, float* __restrict__ out)
{
    int idx = blockIdx.x * 256 + threadIdx.x;
    if (idx >= 1024 * 1536) return;
    int c = idx % 1536, r = idx / 1536;
    int b = r >> 8, i = r & 255;
    float v;
    if (c < 512)       v = l0[(size_t)r * 512 + c];
    else if (c < 1024) v = l1[(size_t)(b * 128 + (i >> 1)) * 512 + c - 512];
    else               v = l2[(size_t)(b * 64 + (i >> 2)) * 512 + c - 1024];
    out[idx] = v;
}

// ---------------------------------------------------------------------------
// LayerNorm over D=512, one wave per row, f64 stats
// ---------------------------------------------------------------------------
__global__ __launch_bounds__(64) void ln_kernel(
    const float* __restrict__ X, const float* __restrict__ g,
    const float* __restrict__ bta, float* __restrict__ Y)
{
    const int row = blockIdx.x, lane = threadIdx.x;
    const float* x = X + (size_t)row * 512;
    float v[8];
    double sum = 0.0;
    #pragma unroll
    for (int t = 0; t < 8; ++t) { v[t] = x[t * 64 + lane]; sum += (double)v[t]; }
    #pragma unroll
    for (int off = 32; off; off >>= 1) sum += __shfl_xor(sum, off);
    const double mean = sum * (1.0 / 512.0);
    double ss = 0.0;
    #pragma unroll
    for (int t = 0; t < 8; ++t) { double d = (double)v[t] - mean; ss += d * d; }
    #pragma unroll
    for (int off = 32; off; off >>= 1) ss += __shfl_xor(ss, off);
    const double rstd = 1.0 / sqrt(ss * (1.0 / 512.0) + 1e-5);
    #pragma unroll
    for (int t = 0; t < 8; ++t) {
        int d = t * 64 + lane;
        Y[(size_t)row * 512 + d] =
            (float)(((double)v[t] - mean) * rstd) * g[d] + bta[d];
    }
}

// ---------------------------------------------------------------------------
// Edge scores: S[b,i,j] = sigmoid(sum_d relu(hi[b,i,d]+hj[b,j,d])*We2[d]+be2)
// ---------------------------------------------------------------------------
__global__ __launch_bounds__(256) void scores_kernel(
    const float* __restrict__ hi, const float* __restrict__ hj,
    const float* __restrict__ We2, const float* __restrict__ be2,
    float* __restrict__ S)
{
    const int i = blockIdx.x, b = blockIdx.y;
    const int lane = threadIdx.x & 63, wave = threadIdx.x >> 6;
    __shared__ float hrow[512];
    __shared__ float w2[512];
    for (int t = threadIdx.x; t < 512; t += 256) {
        hrow[t] = hi[(size_t)(b * 256 + i) * 512 + t];
        w2[t] = We2[t];
    }
    __syncthreads();
    const double bb = (double)be2[0];
    for (int j = wave; j < 256; j += 4) {
        const float* hjp = hj + (size_t)(b * 256 + j) * 512;
        double acc = 0.0;
        #pragma unroll
        for (int t = 0; t < 8; ++t) {
            int d = t * 64 + lane;
            float pre = hrow[d] + hjp[d];
            acc += (double)fmaxf(pre, 0.f) * (double)w2[d];
        }
        #pragma unroll
        for (int off = 32; off; off >>= 1) acc += __shfl_xor(acc, off);
        if (lane == 0) {
            double z = acc + bb;
            float sc = (float)(1.0 / (1.0 + exp(-z)));
            if (j == i) sc = 0.f;
            S[(size_t)(b * 256 + i) * 256 + j] = sc;
        }
    }
}

// ---------------------------------------------------------------------------
// Top-k(25) one-hot per row of 256 (ties -> lower index, like lax.top_k).
// ---------------------------------------------------------------------------
__global__ __launch_bounds__(64) void topk_kernel(
    const float* __restrict__ S, float* __restrict__ out)
{
    const int row = blockIdx.x;       // b*256+i
    const int lane = threadIdx.x;
    float v[4]; int sel[4] = {0, 0, 0, 0};
    #pragma unroll
    for (int t = 0; t < 4; ++t) v[t] = S[(size_t)row * 256 + t * 64 + lane];
    for (int it = 0; it < 25; ++it) {
        float bv = v[0]; int bi = lane;
        #pragma unroll
        for (int t = 1; t < 4; ++t) {
            int idx = t * 64 + lane;
            if (v[t] > bv) { bv = v[t]; bi = idx; }
        }
        #pragma unroll
        for (int off = 32; off; off >>= 1) {
            float ov = __shfl_xor(bv, off);
            int   oi = __shfl_xor(bi, off);
            if (ov > bv || (ov == bv && oi < bi)) { bv = ov; bi = oi; }
        }
        if ((bi & 63) == lane) { int t = bi >> 6; sel[t] = 1; v[t] = -INFINITY; }
    }
    #pragma unroll
    for (int t = 0; t < 4; ++t)
        out[(size_t)row * 256 + t * 64 + lane] = (float)sel[t];
}

// ---------------------------------------------------------------------------
extern "C" void kernel_launch(void* const* d_in, const int* in_sizes, int n_in,
                              void* d_out, int out_size, void* d_ws, size_t ws_size,
                              hipStream_t stream)
{
    const float* x      = (const float*)d_in[0];
    const float* Wqkv   = (const float*)d_in[2];
    const float* bqkv   = (const float*)d_in[3];
    const float* Wo     = (const float*)d_in[4];
    const float* bo     = (const float*)d_in[5];
    const float* Wp1    = (const float*)d_in[6];
    const float* bp1    = (const float*)d_in[7];
    const float* Wp2    = (const float*)d_in[8];
    const float* bp2    = (const float*)d_in[9];
    const float* Wfuse  = (const float*)d_in[10];
    const float* bfuse  = (const float*)d_in[11];
    const float* ln_g   = (const float*)d_in[12];
    const float* ln_b   = (const float*)d_in[13];
    const float* We1    = (const float*)d_in[14];
    const float* be1    = (const float*)d_in[15];
    const float* We2    = (const float*)d_in[16];
    const float* be2    = (const float*)d_in[17];
    const float* Ws_qkv = (const float*)d_in[18];
    const float* bs_qkv = (const float*)d_in[19];
    const float* Ws_o   = (const float*)d_in[20];
    const float* bs_o   = (const float*)d_in[21];

    float* out_att    = (float*)d_out;               // 4*256*512
    float* out_sparse = out_att + 4 * 256 * 512;     // 4*256*256

    // workspace layout (floats)
    float* ws   = (float*)d_ws;
    float* qkvb = ws;                    // 1,572,864  (also reused as concat)
    float* attnb = qkvb + 1572864;       //   524,288
    float* lvl0 = attnb + 524288;        //   524,288
    float* lvl1 = lvl0 + 524288;         //   262,144
    float* lvl2 = lvl1 + 262144;         //   131,072
    float* curb = lvl2 + 131072;         //   262,144
    float* phb  = curb + 262144;         //   262,144
    float* hier = phb + 262144;          //   524,288
    float* hib  = hier + 524288;         //   524,288
    float* hjb  = hib + 524288;          //   524,288
    float* scb  = hjb + 524288;          //   262,144

    auto G = [&](const float* A, const float* W, const float* bias, float* C,
                 int M, int N, int K, int relu) {
        gemm_t<double><<<dim3(N / 64, M / 64), 256, 0, stream>>>(A, W, bias, C, M, N, K, relu);
    };
    auto Gf = [&](const float* A, const float* W, const float* bias, float* C,
                  int M, int N, int K, int relu) {
        gemm_t<float><<<dim3(N / 64, M / 64), 256, 0, stream>>>(A, W, bias, C, M, N, K, relu);
    };

    // ---- Level 0 (n=256) ----
    G(x, Wqkv, bqkv, qkvb, 1024, 1536, 512, 0);
    attn_fused<<<dim3(64, 8, 4), 256, 0, stream>>>(qkvb, attnb, 256);
    G(attnb, Wo, bo, lvl0, 1024, 512, 512, 0);
    G(lvl0, Wp1, bp1, phb, 1024, 256, 512, 1);
    G(phb, Wp2, bp2, attnb, 1024, 512, 256, 0);
    pool_kernel<<<(4 * 128 * 512 + 255) / 256, 256, 0, stream>>>(attnb, curb, 128);

    // ---- Level 1 (n=128) ----
    G(curb, Wqkv + 512 * 1536, bqkv + 1536, qkvb, 512, 1536, 512, 0);
    attn_fused<<<dim3(32, 8, 4), 256, 0, stream>>>(qkvb, attnb, 128);
    G(attnb, Wo + 512 * 512, bo + 512, lvl1, 512, 512, 512, 0);
    G(lvl1, Wp1 + 512 * 256, bp1 + 256, phb, 512, 256, 512, 1);
    G(phb, Wp2 + 256 * 512, bp2 + 512, attnb, 512, 512, 256, 0);
    pool_kernel<<<(4 * 64 * 512 + 255) / 256, 256, 0, stream>>>(attnb, curb, 64);

    // ---- Level 2 (n=64) ----
    G(curb, Wqkv + 2 * 512 * 1536, bqkv + 2 * 1536, qkvb, 256, 1536, 512, 0);
    attn_fused<<<dim3(16, 8, 4), 256, 0, stream>>>(qkvb, attnb, 64);
    G(attnb, Wo + 2 * 512 * 512, bo + 2 * 512, lvl2, 256, 512, 512, 0);

    // ---- Fuse + LN ----
    concat_kernel<<<(1024 * 1536 + 255) / 256, 256, 0, stream>>>(lvl0, lvl1, lvl2, qkvb);
    G(qkvb, Wfuse, bfuse, attnb, 1024, 512, 1536, 1);
    ln_kernel<<<1024, 64, 0, stream>>>(attnb, ln_g, ln_b, hier);

    // ---- Sparse edge scoring + top-k (precision-critical: f64) ----
    G(hier, We1, nullptr, hib, 1024, 512, 512, 0);
    G(hier, We1 + 512 * 512, be1, hjb, 1024, 512, 512, 0);
    scores_kernel<<<dim3(256, 4), 256, 0, stream>>>(hib, hjb, We2, be2, scb);
    topk_kernel<<<1024, 64, 0, stream>>>(scb, out_sparse);

    // ---- Final MHA on hier (feeds only output 0, tol 2e-2 -> f32 GEMMs) ----
    Gf(hier, Ws_qkv, bs_qkv, qkvb, 1024, 1536, 512, 0);
    attn_fused<<<dim3(64, 8, 4), 256, 0, stream>>>(qkvb, attnb, 256);
    Gf(attnb, Ws_o, bs_o, out_att, 1024, 512, 512, 0);
}

// Round 3
// 695.301 us; speedup vs baseline: 2.1751x; 1.3994x over previous
//
#include <hip/hip_runtime.h>
#include <math.h>

// Problem constants: B=4, N=256, D=512, H=8, HD=64, L=3, K_SPARSE=25, EPS=1e-5

// ---------------------------------------------------------------------------
// GEMM v2: C[M,N] = act(A[M,K] @ W[K,N] + bias). ACC = double (score path)
// or float (final MHA). LDS tiles pre-converted to ACC; conflict-free Ws
// layout [16][4][17]; register prefetch of next k-tile.
// TM = 32 or 64 rows per block; 64 cols; 256 threads; thread owns
// RT=TM/16 rows x 4 cols (cols j*16+tx, j=0..3).
// flags: 1 = relu, 2 = pool (pair-average rows of activated output, C gets M/2 rows)
// wmode: 0 none; 1 = fuse3 (W += seg(bm)*512*512, segs at rows 1024/1536);
//        2 = we1-split (bn>=512 -> W += 512*512 & bias applies; else no bias)
// ---------------------------------------------------------------------------
template <int TM, typename ACC>
__global__ __launch_bounds__(256) void gemm_v2(
    const float* __restrict__ A, const float* __restrict__ W,
    const float* __restrict__ bias, float* __restrict__ C,
    int M, int N, int K, int flags, int wmode)
{
    constexpr int RT = TM / 16;
    constexpr int AV = (TM == 64) ? 4 : 2;   // A floats staged per thread
    __shared__ ACC As[16][TM];
    __shared__ ACC Ws[16][4][17];

    const int tid = threadIdx.x;
    const int tx = tid & 15, ty = tid >> 4;
    const int bm = blockIdx.y * TM, bn = blockIdx.x * 64;

    const float* Wp = W;
    const float* bp = bias;
    if (wmode == 1) {
        int seg = (bm >= 1536) ? 2 : (bm >= 1024) ? 1 : 0;
        Wp += (size_t)seg * 262144;
    } else if (wmode == 2) {
        if (bn >= 512) Wp += 262144; else bp = nullptr;
    }
    const int wn = (wmode == 2) ? 512 : N;   // W row stride
    const int wc = (wmode == 2) ? (bn & 511) : bn;

    // staging thread mapping
    const int ar = (TM == 64) ? (tid >> 2) : (tid >> 3);
    const int ac = (TM == 64) ? ((tid & 3) << 2) : ((tid & 7) << 1);
    const int wr = tid >> 4;                 // 0..15 (k row)
    const int wcc = (tid & 15) << 2;         // 0..60 (col in block)
    const int wj = wcc >> 4, wk = wcc & 15;

    const float* Aptr = A + (size_t)(bm + ar) * K + ac;
    const float* Wptr = Wp + (size_t)wr * wn + wc + wcc;

    ACC acc[RT][4] = {};
    float ra[AV], rw[4];

    // initial prefetch (k0 = 0)
    {
        if (TM == 64) { float4 v = *(const float4*)Aptr;
            ra[0]=v.x; ra[1]=v.y; ra[2]=v.z; ra[3]=v.w; }
        else { float2 v = *(const float2*)Aptr; ra[0]=v.x; ra[1]=v.y; }
        float4 w = *(const float4*)Wptr;
        rw[0]=w.x; rw[1]=w.y; rw[2]=w.z; rw[3]=w.w;
    }

    for (int k0 = 0; k0 < K; k0 += 16) {
        if (k0) __syncthreads();
        #pragma unroll
        for (int u = 0; u < AV; ++u) As[ac + u][ar] = (ACC)ra[u];
        #pragma unroll
        for (int u = 0; u < 4; ++u) Ws[wr][wj][wk + u] = (ACC)rw[u];
        __syncthreads();

        if (k0 + 16 < K) {   // prefetch next tile into regs
            const float* ap = Aptr + k0 + 16;
            if (TM == 64) { float4 v = *(const float4*)ap;
                ra[0]=v.x; ra[1]=v.y; ra[2]=v.z; ra[3]=v.w; }
            else { float2 v = *(const float2*)ap; ra[0]=v.x; ra[1]=v.y; }
            float4 w = *(const float4*)(Wptr + (size_t)(k0 + 16) * wn);
            rw[0]=w.x; rw[1]=w.y; rw[2]=w.z; rw[3]=w.w;
        }

        #pragma unroll
        for (int kk = 0; kk < 16; ++kk) {
            ACC a[RT], w[4];
            #pragma unroll
            for (int i = 0; i < RT; ++i) a[i] = As[kk][ty * RT + i];
            #pragma unroll
            for (int j = 0; j < 4; ++j) w[j] = Ws[kk][j][tx];
            #pragma unroll
            for (int i = 0; i < RT; ++i)
                #pragma unroll
                for (int j = 0; j < 4; ++j)
                    acc[i][j] += a[i] * w[j];
        }
    }

    // epilogue
    #pragma unroll
    for (int j = 0; j < 4; ++j) {
        const int cn = bn + j * 16 + tx;
        const ACC bv = bp ? (ACC)bp[wc + j * 16 + tx] : (ACC)0;
        if (flags & 2) {   // pool: pair-average activated rows
            #pragma unroll
            for (int pi = 0; pi < RT / 2; ++pi) {
                ACC f0 = acc[2 * pi][j] + bv;
                ACC f1 = acc[2 * pi + 1][j] + bv;
                if (flags & 1) {
                    f0 = f0 > (ACC)0 ? f0 : (ACC)0;
                    f1 = f1 > (ACC)0 ? f1 : (ACC)0;
                }
                int prow = ((bm + ty * RT) >> 1) + pi;
                C[(size_t)prow * N + cn] = (float)((f0 + f1) * (ACC)0.5);
            }
        } else {
            #pragma unroll
            for (int i = 0; i < RT; ++i) {
                ACC f = acc[i][j] + bv;
                if (flags & 1) f = f > (ACC)0 ? f : (ACC)0;
                C[(size_t)(bm + ty * RT + i) * N + cn] = (float)f;
            }
        }
    }
}

// ---------------------------------------------------------------------------
// Fused MHA core: out[b,i,h*64+d] = softmax(QK^T * 0.125) V
// qkv layout [B][n][1536] (q | k | v). Block = (4 q-rows, h, b), 4 waves.
// ---------------------------------------------------------------------------
__global__ __launch_bounds__(256) void attn_fused(
    const float* __restrict__ qkv, float* __restrict__ out, int n)
{
    const int lane = threadIdx.x & 63;
    const int w    = threadIdx.x >> 6;
    const int h = blockIdx.y, b = blockIdx.z;
    const int qi = blockIdx.x * 4 + w;
    const int nt = n >> 6;
    const size_t base = (size_t)b * n * 1536;

    __shared__ float q_lds[4][64];
    __shared__ float kv_lds[64][65];
    __shared__ float p_lds[4][256];

    q_lds[w][lane] = qkv[base + (size_t)qi * 1536 + h * 64 + lane];

    float s[4];
    for (int t = 0; t < nt; ++t) {
        const int j0 = t * 64;
        __syncthreads();
        {
            int r = threadIdx.x >> 2;
            int q4 = threadIdx.x & 3;
            const float* src = qkv + base + (size_t)(j0 + r) * 1536 + 512 + h * 64;
            #pragma unroll
            for (int u = 0; u < 4; ++u) {
                int c = u * 4 + q4;
                float4 v = *(const float4*)(src + c * 4);
                kv_lds[r][c * 4 + 0] = v.x; kv_lds[r][c * 4 + 1] = v.y;
                kv_lds[r][c * 4 + 2] = v.z; kv_lds[r][c * 4 + 3] = v.w;
            }
        }
        __syncthreads();
        float a0 = 0.f, a1 = 0.f, a2 = 0.f, a3 = 0.f;
        #pragma unroll
        for (int d = 0; d < 64; d += 4) {
            a0 += q_lds[w][d + 0] * kv_lds[lane][d + 0];
            a1 += q_lds[w][d + 1] * kv_lds[lane][d + 1];
            a2 += q_lds[w][d + 2] * kv_lds[lane][d + 2];
            a3 += q_lds[w][d + 3] * kv_lds[lane][d + 3];
        }
        s[t] = ((a0 + a1) + (a2 + a3)) * 0.125f;
    }

    float m = s[0];
    for (int t = 1; t < nt; ++t) m = fmaxf(m, s[t]);
    #pragma unroll
    for (int off = 32; off; off >>= 1) m = fmaxf(m, __shfl_xor(m, off));
    float p[4];
    double sum = 0.0;
    for (int t = 0; t < nt; ++t) { p[t] = expf(s[t] - m); sum += (double)p[t]; }
    #pragma unroll
    for (int off = 32; off; off >>= 1) sum += __shfl_xor(sum, off);
    const double inv = 1.0 / sum;
    for (int t = 0; t < nt; ++t) p_lds[w][t * 64 + lane] = p[t];

    double acc = 0.0;
    for (int t = 0; t < nt; ++t) {
        const int j0 = t * 64;
        __syncthreads();
        {
            int r = threadIdx.x >> 2;
            int q4 = threadIdx.x & 3;
            const float* src = qkv + base + (size_t)(j0 + r) * 1536 + 1024 + h * 64;
            #pragma unroll
            for (int u = 0; u < 4; ++u) {
                int c = u * 4 + q4;
                float4 v = *(const float4*)(src + c * 4);
                kv_lds[r][c * 4 + 0] = v.x; kv_lds[r][c * 4 + 1] = v.y;
                kv_lds[r][c * 4 + 2] = v.z; kv_lds[r][c * 4 + 3] = v.w;
            }
        }
        __syncthreads();
        #pragma unroll 8
        for (int jl = 0; jl < 64; ++jl)
            acc += (double)p_lds[w][j0 + jl] * (double)kv_lds[jl][lane];
    }
    out[((size_t)(b * n + qi)) * 512 + h * 64 + lane] = (float)(acc * inv);
}

// ---------------------------------------------------------------------------
// Fused 3-way add + bias + relu + LayerNorm. y = [y0(1024r) | y1(512r) | y2(256r)]
// row r=(b,i): preln = relu(y0[r] + y1[1024+b*128+i/2] + y2[1536+b*64+i/4] + bf)
// ---------------------------------------------------------------------------
__global__ __launch_bounds__(64) void ln3_kernel(
    const float* __restrict__ y, const float* __restrict__ bf,
    const float* __restrict__ g, const float* __restrict__ bta,
    float* __restrict__ out)
{
    const int r = blockIdx.x, lane = threadIdx.x;
    const int b = r >> 8, i = r & 255;
    const float* y0 = y + (size_t)r * 512;
    const float* y1 = y + (size_t)(1024 + b * 128 + (i >> 1)) * 512;
    const float* y2 = y + (size_t)(1536 + b * 64 + (i >> 2)) * 512;
    double v[8];
    double sum = 0.0;
    #pragma unroll
    for (int t = 0; t < 8; ++t) {
        int d = t * 64 + lane;
        double s = (double)y0[d] + (double)y1[d] + (double)y2[d] + (double)bf[d];
        s = s > 0.0 ? s : 0.0;
        v[t] = s; sum += s;
    }
    #pragma unroll
    for (int off = 32; off; off >>= 1) sum += __shfl_xor(sum, off);
    const double mean = sum * (1.0 / 512.0);
    double ss = 0.0;
    #pragma unroll
    for (int t = 0; t < 8; ++t) { double d = v[t] - mean; ss += d * d; }
    #pragma unroll
    for (int off = 32; off; off >>= 1) ss += __shfl_xor(ss, off);
    const double rstd = 1.0 / sqrt(ss * (1.0 / 512.0) + 1e-5);
    #pragma unroll
    for (int t = 0; t < 8; ++t) {
        int d = t * 64 + lane;
        out[(size_t)r * 512 + d] =
            (float)((v[t] - mean) * rstd * (double)g[d] + (double)bta[d]);
    }
}

// ---------------------------------------------------------------------------
// Edge scores from combined hibjb[1024][1024] (cols 0:512 = hi, 512:1024 = hj)
// S[b,i,j] = sigmoid(sum_d relu(hi[b,i,d]+hj[b,j,d])*We2[d]+be2); diag = 0
// ---------------------------------------------------------------------------
__global__ __launch_bounds__(256) void scores_kernel(
    const float* __restrict__ hibjb, const float* __restrict__ We2,
    const float* __restrict__ be2, float* __restrict__ S)
{
    const int i = blockIdx.x, b = blockIdx.y;
    const int lane = threadIdx.x & 63, wave = threadIdx.x >> 6;
    __shared__ float hrow[512];
    __shared__ float w2[512];
    for (int t = threadIdx.x; t < 512; t += 256) {
        hrow[t] = hibjb[(size_t)(b * 256 + i) * 1024 + t];
        w2[t] = We2[t];
    }
    __syncthreads();
    const double bb = (double)be2[0];
    for (int j = wave; j < 256; j += 4) {
        const float* hjp = hibjb + (size_t)(b * 256 + j) * 1024 + 512;
        double acc = 0.0;
        #pragma unroll
        for (int t = 0; t < 8; ++t) {
            int d = t * 64 + lane;
            float pre = hrow[d] + hjp[d];
            acc += (double)fmaxf(pre, 0.f) * (double)w2[d];
        }
        #pragma unroll
        for (int off = 32; off; off >>= 1) acc += __shfl_xor(acc, off);
        if (lane == 0) {
            double z = acc + bb;
            float sc = (float)(1.0 / (1.0 + exp(-z)));
            if (j == i) sc = 0.f;
            S[(size_t)(b * 256 + i) * 256 + j] = sc;
        }
    }
}

// ---------------------------------------------------------------------------
// Top-k(25) one-hot per row of 256 (ties -> lower index, like lax.top_k).
// ---------------------------------------------------------------------------
__global__ __launch_bounds__(64) void topk_kernel(
    const float* __restrict__ S, float* __restrict__ out)
{
    const int row = blockIdx.x;
    const int lane = threadIdx.x;
    float v[4]; int sel[4] = {0, 0, 0, 0};
    #pragma unroll
    for (int t = 0; t < 4; ++t) v[t] = S[(size_t)row * 256 + t * 64 + lane];
    for (int it = 0; it < 25; ++it) {
        float bv = v[0]; int bi = lane;
        #pragma unroll
        for (int t = 1; t < 4; ++t) {
            int idx = t * 64 + lane;
            if (v[t] > bv) { bv = v[t]; bi = idx; }
        }
        #pragma unroll
        for (int off = 32; off; off >>= 1) {
            float ov = __shfl_xor(bv, off);
            int   oi = __shfl_xor(bi, off);
            if (ov > bv || (ov == bv && oi < bi)) { bv = ov; bi = oi; }
        }
        if ((bi & 63) == lane) { int t = bi >> 6; sel[t] = 1; v[t] = -INFINITY; }
    }
    #pragma unroll
    for (int t = 0; t < 4; ++t)
        out[(size_t)row * 256 + t * 64 + lane] = (float)sel[t];
}

// ---------------------------------------------------------------------------
extern "C" void kernel_launch(void* const* d_in, const int* in_sizes, int n_in,
                              void* d_out, int out_size, void* d_ws, size_t ws_size,
                              hipStream_t stream)
{
    const float* x      = (const float*)d_in[0];
    const float* Wqkv   = (const float*)d_in[2];
    const float* bqkv   = (const float*)d_in[3];
    const float* Wo     = (const float*)d_in[4];
    const float* bo     = (const float*)d_in[5];
    const float* Wp1    = (const float*)d_in[6];
    const float* bp1    = (const float*)d_in[7];
    const float* Wp2    = (const float*)d_in[8];
    const float* bp2    = (const float*)d_in[9];
    const float* Wfuse  = (const float*)d_in[10];
    const float* bfuse  = (const float*)d_in[11];
    const float* ln_g   = (const float*)d_in[12];
    const float* ln_b   = (const float*)d_in[13];
    const float* We1    = (const float*)d_in[14];
    const float* be1    = (const float*)d_in[15];
    const float* We2    = (const float*)d_in[16];
    const float* be2    = (const float*)d_in[17];
    const float* Ws_qkv = (const float*)d_in[18];
    const float* bs_qkv = (const float*)d_in[19];
    const float* Ws_o   = (const float*)d_in[20];
    const float* bs_o   = (const float*)d_in[21];

    float* out_att    = (float*)d_out;               // 4*256*512
    float* out_sparse = out_att + 4 * 256 * 512;     // 4*256*256

    // workspace layout (floats), total 5,242,880 fl = 21.0 MB
    float* ws    = (float*)d_ws;
    float* qkvb  = ws;                    // 1,572,864 (also y-buffer for fuse3)
    float* attnb = qkvb + 1572864;        //   524,288
    float* lvls  = attnb + 524288;        //   917,504 (lvl0 | lvl1 | lvl2)
    float* poolb = lvls + 917504;         //   131,072
    float* curb  = poolb + 131072;        //   262,144
    float* hier  = curb + 262144;         //   524,288
    float* hibjb = hier + 524288;         // 1,048,576
    float* scb   = hibjb + 1048576;       //   262,144

    float* lvl0 = lvls;
    float* lvl1 = lvls + 1024 * 512;
    float* lvl2 = lvls + 1536 * 512;

    auto G64 = [&](const float* A, const float* W, const float* bias, float* C,
                   int M, int N, int K, int flags, int wmode) {
        gemm_v2<64, double><<<dim3(N / 64, M / 64), 256, 0, stream>>>(
            A, W, bias, C, M, N, K, flags, wmode);
    };
    auto G32 = [&](const float* A, const float* W, const float* bias, float* C,
                   int M, int N, int K, int flags, int wmode) {
        gemm_v2<32, double><<<dim3(N / 64, M / 32), 256, 0, stream>>>(
            A, W, bias, C, M, N, K, flags, wmode);
    };
    auto G32f = [&](const float* A, const float* W, const float* bias, float* C,
                    int M, int N, int K, int flags, int wmode) {
        gemm_v2<32, float><<<dim3(N / 64, M / 32), 256, 0, stream>>>(
            A, W, bias, C, M, N, K, flags, wmode);
    };

    // ---- Level 0 (n=256) ----
    G64(x, Wqkv, bqkv, qkvb, 1024, 1536, 512, 0, 0);
    attn_fused<<<dim3(64, 8, 4), 256, 0, stream>>>(qkvb, attnb, 256);
    G32(attnb, Wo, bo, lvl0, 1024, 512, 512, 0, 0);
    G32(lvl0, Wp1, bp1, poolb, 1024, 256, 512, 3, 0);     // relu+pool -> [512][256]
    G32(poolb, Wp2, bp2, curb, 512, 512, 256, 0, 0);

    // ---- Level 1 (n=128) ----
    G32(curb, Wqkv + 512 * 1536, bqkv + 1536, qkvb, 512, 1536, 512, 0, 0);
    attn_fused<<<dim3(32, 8, 4), 256, 0, stream>>>(qkvb, attnb, 128);
    G32(attnb, Wo + 512 * 512, bo + 512, lvl1, 512, 512, 512, 0, 0);
    G32(lvl1, Wp1 + 512 * 256, bp1 + 256, poolb, 512, 256, 512, 3, 0);  // -> [256][256]
    G32(poolb, Wp2 + 256 * 512, bp2 + 512, curb, 256, 512, 256, 0, 0);

    // ---- Level 2 (n=64) ----
    G32(curb, Wqkv + 2 * 512 * 1536, bqkv + 2 * 1536, qkvb, 256, 1536, 512, 0, 0);
    attn_fused<<<dim3(16, 8, 4), 256, 0, stream>>>(qkvb, attnb, 64);
    G32(attnb, Wo + 2 * 512 * 512, bo + 2 * 512, lvl2, 256, 512, 512, 0, 0);

    // ---- Fuse (batched partial GEMM) + LN ----
    G32(lvls, Wfuse, nullptr, qkvb, 1792, 512, 512, 0, 1);   // y -> qkvb
    ln3_kernel<<<1024, 64, 0, stream>>>(qkvb, bfuse, ln_g, ln_b, hier);

    // ---- Sparse edge scoring + top-k (precision-critical: f64) ----
    G32(hier, We1, be1, hibjb, 1024, 1024, 512, 0, 2);       // [hi | hj]
    scores_kernel<<<dim3(256, 4), 256, 0, stream>>>(hibjb, We2, be2, scb);
    topk_kernel<<<1024, 64, 0, stream>>>(scb, out_sparse);

    // ---- Final MHA on hier (feeds only output 0, tol 2e-2 -> f32) ----
    G32f(hier, Ws_qkv, bs_qkv, qkvb, 1024, 1536, 512, 0, 0);
    attn_fused<<<dim3(64, 8, 4), 256, 0, stream>>>(qkvb, attnb, 256);
    G32f(attnb, Ws_o, bs_o, out_att, 1024, 512, 512, 0, 0);
}

// Round 4
// 548.850 us; speedup vs baseline: 2.7555x; 1.2668x over previous
//
#include <hip/hip_runtime.h>
#include <math.h>

// Problem constants: B=4, N=256, D=512, H=8, HD=64, L=3, K_SPARSE=25, EPS=1e-5

// ---------------------------------------------------------------------------
// GEMM v3: C[M,N] = act(A[M,K] @ W[K,N] + bias). Thread owns RT=TM/16
// consecutive rows x 4 consecutive cols -> vectorized LDS fragment reads.
// flags: 1 = relu, 2 = pool (pair-average rows, C gets M/2 rows),
//        4 = transpose-out (C[col*M + row])
// wmode: 0 none; 1 = fuse3 (W += seg(bm)*512*512, seg rows at 1024/1536)
// ---------------------------------------------------------------------------
template <int TM, typename ACC>
__global__ __launch_bounds__(256) void gemm_v3(
    const float* __restrict__ A, const float* __restrict__ W,
    const float* __restrict__ bias, float* __restrict__ C,
    int M, int N, int K, int flags, int wmode)
{
    constexpr int RT = TM / 16;
    constexpr int PAD = (sizeof(ACC) == 4) ? 4 : 2;
    __shared__ ACC As[16][TM + PAD];
    __shared__ ACC Ws[16][64 + PAD];

    const int tid = threadIdx.x;
    const int tx = tid & 15, ty = tid >> 4;
    const int bm = blockIdx.y * TM, bn = blockIdx.x * 64;

    const float* Wp = W;
    if (wmode == 1) {
        int seg = (bm >= 1536) ? 2 : (bm >= 1024) ? 1 : 0;
        Wp += (size_t)seg * 262144;
    }

    constexpr int AV = (TM == 64) ? 4 : 2;
    const int ar = (TM == 64) ? (tid >> 2) : (tid >> 3);
    const int ac = (TM == 64) ? ((tid & 3) << 2) : ((tid & 7) << 1);
    const int wr = tid >> 4;
    const int wc = (tid & 15) << 2;

    const float* Aptr = A + (size_t)(bm + ar) * K + ac;
    const float* Wptr = Wp + (size_t)wr * N + bn + wc;

    ACC acc[RT][4] = {};
    float ra[AV], rw[4];

    {   // initial prefetch (k0 = 0)
        if (TM == 64) { float4 v = *(const float4*)Aptr;
            ra[0]=v.x; ra[1]=v.y; ra[2]=v.z; ra[3]=v.w; }
        else { float2 v = *(const float2*)Aptr; ra[0]=v.x; ra[1]=v.y; }
        float4 w = *(const float4*)Wptr;
        rw[0]=w.x; rw[1]=w.y; rw[2]=w.z; rw[3]=w.w;
    }

    for (int k0 = 0; k0 < K; k0 += 16) {
        if (k0) __syncthreads();
        #pragma unroll
        for (int u = 0; u < AV; ++u) As[ac + u][ar] = (ACC)ra[u];
        #pragma unroll
        for (int u = 0; u < 4; ++u) Ws[wr][wc + u] = (ACC)rw[u];
        __syncthreads();

        if (k0 + 16 < K) {
            const float* ap = Aptr + k0 + 16;
            if (TM == 64) { float4 v = *(const float4*)ap;
                ra[0]=v.x; ra[1]=v.y; ra[2]=v.z; ra[3]=v.w; }
            else { float2 v = *(const float2*)ap; ra[0]=v.x; ra[1]=v.y; }
            float4 w = *(const float4*)(Wptr + (size_t)(k0 + 16) * N);
            rw[0]=w.x; rw[1]=w.y; rw[2]=w.z; rw[3]=w.w;
        }

        #pragma unroll
        for (int kk = 0; kk < 16; ++kk) {
            ACC a[RT], w[4];
            #pragma unroll
            for (int i = 0; i < RT; ++i) a[i] = As[kk][ty * RT + i];
            #pragma unroll
            for (int j = 0; j < 4; ++j) w[j] = Ws[kk][tx * 4 + j];
            #pragma unroll
            for (int i = 0; i < RT; ++i)
                #pragma unroll
                for (int j = 0; j < 4; ++j)
                    acc[i][j] += a[i] * w[j];
        }
    }

    // epilogue
    #pragma unroll
    for (int j = 0; j < 4; ++j) {
        const int cn = bn + tx * 4 + j;
        const ACC bv = bias ? (ACC)bias[cn] : (ACC)0;
        if (flags & 2) {   // pool: pair-average activated rows
            #pragma unroll
            for (int pi = 0; pi < RT / 2; ++pi) {
                ACC f0 = acc[2 * pi][j] + bv;
                ACC f1 = acc[2 * pi + 1][j] + bv;
                if (flags & 1) {
                    f0 = f0 > (ACC)0 ? f0 : (ACC)0;
                    f1 = f1 > (ACC)0 ? f1 : (ACC)0;
                }
                int prow = ((bm + ty * RT) >> 1) + pi;
                C[(size_t)prow * N + cn] = (float)((f0 + f1) * (ACC)0.5);
            }
        } else if (flags & 4) {   // transpose-out
            #pragma unroll
            for (int i = 0; i < RT; ++i) {
                ACC f = acc[i][j] + bv;
                if (flags & 1) f = f > (ACC)0 ? f : (ACC)0;
                C[(size_t)cn * M + bm + ty * RT + i] = (float)f;
            }
        } else {
            #pragma unroll
            for (int i = 0; i < RT; ++i) {
                ACC f = acc[i][j] + bv;
                if (flags & 1) f = f > (ACC)0 ? f : (ACC)0;
                C[(size_t)(bm + ty * RT + i) * N + cn] = (float)f;
            }
        }
    }
}

// ---------------------------------------------------------------------------
// Fused MHA core: out[b,i,h*64+d] = softmax(QK^T * 0.125) V
// qkv layout [B][n][1536] (q | k | v). Block = (4 q-rows, h, b), 4 waves.
// ---------------------------------------------------------------------------
__global__ __launch_bounds__(256) void attn_fused(
    const float* __restrict__ qkv, float* __restrict__ out, int n)
{
    const int lane = threadIdx.x & 63;
    const int w    = threadIdx.x >> 6;
    const int h = blockIdx.y, b = blockIdx.z;
    const int qi = blockIdx.x * 4 + w;
    const int nt = n >> 6;
    const size_t base = (size_t)b * n * 1536;

    __shared__ float q_lds[4][64];
    __shared__ float kv_lds[64][65];
    __shared__ float p_lds[4][256];

    q_lds[w][lane] = qkv[base + (size_t)qi * 1536 + h * 64 + lane];

    float s[4];
    for (int t = 0; t < nt; ++t) {
        const int j0 = t * 64;
        __syncthreads();
        {
            int r = threadIdx.x >> 2;
            int q4 = threadIdx.x & 3;
            const float* src = qkv + base + (size_t)(j0 + r) * 1536 + 512 + h * 64;
            #pragma unroll
            for (int u = 0; u < 4; ++u) {
                int c = u * 4 + q4;
                float4 v = *(const float4*)(src + c * 4);
                kv_lds[r][c * 4 + 0] = v.x; kv_lds[r][c * 4 + 1] = v.y;
                kv_lds[r][c * 4 + 2] = v.z; kv_lds[r][c * 4 + 3] = v.w;
            }
        }
        __syncthreads();
        float a0 = 0.f, a1 = 0.f, a2 = 0.f, a3 = 0.f;
        #pragma unroll
        for (int d = 0; d < 64; d += 4) {
            a0 += q_lds[w][d + 0] * kv_lds[lane][d + 0];
            a1 += q_lds[w][d + 1] * kv_lds[lane][d + 1];
            a2 += q_lds[w][d + 2] * kv_lds[lane][d + 2];
            a3 += q_lds[w][d + 3] * kv_lds[lane][d + 3];
        }
        s[t] = ((a0 + a1) + (a2 + a3)) * 0.125f;
    }

    float m = s[0];
    for (int t = 1; t < nt; ++t) m = fmaxf(m, s[t]);
    #pragma unroll
    for (int off = 32; off; off >>= 1) m = fmaxf(m, __shfl_xor(m, off));
    float p[4];
    double sum = 0.0;
    for (int t = 0; t < nt; ++t) { p[t] = expf(s[t] - m); sum += (double)p[t]; }
    #pragma unroll
    for (int off = 32; off; off >>= 1) sum += __shfl_xor(sum, off);
    const double inv = 1.0 / sum;
    for (int t = 0; t < nt; ++t) p_lds[w][t * 64 + lane] = p[t];

    float acc = 0.f;
    for (int t = 0; t < nt; ++t) {
        const int j0 = t * 64;
        __syncthreads();
        {
            int r = threadIdx.x >> 2;
            int q4 = threadIdx.x & 3;
            const float* src = qkv + base + (size_t)(j0 + r) * 1536 + 1024 + h * 64;
            #pragma unroll
            for (int u = 0; u < 4; ++u) {
                int c = u * 4 + q4;
                float4 v = *(const float4*)(src + c * 4);
                kv_lds[r][c * 4 + 0] = v.x; kv_lds[r][c * 4 + 1] = v.y;
                kv_lds[r][c * 4 + 2] = v.z; kv_lds[r][c * 4 + 3] = v.w;
            }
        }
        __syncthreads();
        #pragma unroll 8
        for (int jl = 0; jl < 64; ++jl)
            acc = fmaf(p_lds[w][j0 + jl], kv_lds[jl][lane], acc);
    }
    out[((size_t)(b * n + qi)) * 512 + h * 64 + lane] = (float)((double)acc * inv);
}

// ---------------------------------------------------------------------------
// Fused 3-way add + bias + relu + LayerNorm. y = [y0(1024r) | y1(512r) | y2(256r)]
// ---------------------------------------------------------------------------
__global__ __launch_bounds__(64) void ln3_kernel(
    const float* __restrict__ y, const float* __restrict__ bf,
    const float* __restrict__ g, const float* __restrict__ bta,
    float* __restrict__ out)
{
    const int r = blockIdx.x, lane = threadIdx.x;
    const int b = r >> 8, i = r & 255;
    const float* y0 = y + (size_t)r * 512;
    const float* y1 = y + (size_t)(1024 + b * 128 + (i >> 1)) * 512;
    const float* y2 = y + (size_t)(1536 + b * 64 + (i >> 2)) * 512;
    double v[8];
    double sum = 0.0;
    #pragma unroll
    for (int t = 0; t < 8; ++t) {
        int d = t * 64 + lane;
        double s = (double)y0[d] + (double)y1[d] + (double)y2[d] + (double)bf[d];
        s = s > 0.0 ? s : 0.0;
        v[t] = s; sum += s;
    }
    #pragma unroll
    for (int off = 32; off; off >>= 1) sum += __shfl_xor(sum, off);
    const double mean = sum * (1.0 / 512.0);
    double ss = 0.0;
    #pragma unroll
    for (int t = 0; t < 8; ++t) { double d = v[t] - mean; ss += d * d; }
    #pragma unroll
    for (int off = 32; off; off >>= 1) ss += __shfl_xor(ss, off);
    const double rstd = 1.0 / sqrt(ss * (1.0 / 512.0) + 1e-5);
    #pragma unroll
    for (int t = 0; t < 8; ++t) {
        int d = t * 64 + lane;
        out[(size_t)r * 512 + d] =
            (float)((v[t] - mean) * rstd * (double)g[d] + (double)bta[d]);
    }
}

// ---------------------------------------------------------------------------
// Edge scores v2: thread-per-j, 4 i-rows per block (staged in LDS), hjT
// coalesced. S[b,i,j] = sigmoid(sum_d relu(hi[i,d]+hj[j,d])*w2[d]+be2); diag 0
// grid: (64 itiles, 4 b), block 256.
// ---------------------------------------------------------------------------
__global__ __launch_bounds__(256) void scores_v2(
    const float* __restrict__ hi,    // [1024][512]
    const float* __restrict__ hjT,   // [512][1024] (d-major)
    const float* __restrict__ We2, const float* __restrict__ be2,
    float* __restrict__ S)
{
    const int b = blockIdx.y;
    const int i0 = blockIdx.x * 4;
    const int j = threadIdx.x;

    __shared__ float hrow[4][512];
    __shared__ float w2[512];
    for (int t = threadIdx.x; t < 512; t += 256) {
        w2[t] = We2[t];
        #pragma unroll
        for (int i = 0; i < 4; ++i)
            hrow[i][t] = hi[(size_t)(b * 256 + i0 + i) * 512 + t];
    }
    __syncthreads();

    const float* hjp = hjT + b * 256 + j;
    double acc[4] = {};
    #pragma unroll 4
    for (int d = 0; d < 512; ++d) {
        float hjv = hjp[(size_t)d * 1024];
        double wv = (double)w2[d];
        #pragma unroll
        for (int i = 0; i < 4; ++i) {
            float pre = fmaxf(hrow[i][d] + hjv, 0.f);
            acc[i] += (double)pre * wv;
        }
    }
    const double bb = (double)be2[0];
    #pragma unroll
    for (int i = 0; i < 4; ++i) {
        double z = acc[i] + bb;
        float sc = (float)(1.0 / (1.0 + exp(-z)));
        if (i0 + i == j) sc = 0.f;
        S[(size_t)(b * 256 + i0 + i) * 256 + j] = sc;
    }
}

// ---------------------------------------------------------------------------
// Top-k(25) one-hot per row of 256 (ties -> lower index, like lax.top_k).
// ---------------------------------------------------------------------------
__global__ __launch_bounds__(64) void topk_kernel(
    const float* __restrict__ S, float* __restrict__ out)
{
    const int row = blockIdx.x;
    const int lane = threadIdx.x;
    float v[4]; int sel[4] = {0, 0, 0, 0};
    #pragma unroll
    for (int t = 0; t < 4; ++t) v[t] = S[(size_t)row * 256 + t * 64 + lane];
    for (int it = 0; it < 25; ++it) {
        float bv = v[0]; int bi = lane;
        #pragma unroll
        for (int t = 1; t < 4; ++t) {
            int idx = t * 64 + lane;
            if (v[t] > bv) { bv = v[t]; bi = idx; }
        }
        #pragma unroll
        for (int off = 32; off; off >>= 1) {
            float ov = __shfl_xor(bv, off);
            int   oi = __shfl_xor(bi, off);
            if (ov > bv || (ov == bv && oi < bi)) { bv = ov; bi = oi; }
        }
        if ((bi & 63) == lane) { int t = bi >> 6; sel[t] = 1; v[t] = -INFINITY; }
    }
    #pragma unroll
    for (int t = 0; t < 4; ++t)
        out[(size_t)row * 256 + t * 64 + lane] = (float)sel[t];
}

// ---------------------------------------------------------------------------
extern "C" void kernel_launch(void* const* d_in, const int* in_sizes, int n_in,
                              void* d_out, int out_size, void* d_ws, size_t ws_size,
                              hipStream_t stream)
{
    const float* x      = (const float*)d_in[0];
    const float* Wqkv   = (const float*)d_in[2];
    const float* bqkv   = (const float*)d_in[3];
    const float* Wo     = (const float*)d_in[4];
    const float* bo     = (const float*)d_in[5];
    const float* Wp1    = (const float*)d_in[6];
    const float* bp1    = (const float*)d_in[7];
    const float* Wp2    = (const float*)d_in[8];
    const float* bp2    = (const float*)d_in[9];
    const float* Wfuse  = (const float*)d_in[10];
    const float* bfuse  = (const float*)d_in[11];
    const float* ln_g   = (const float*)d_in[12];
    const float* ln_b   = (const float*)d_in[13];
    const float* We1    = (const float*)d_in[14];
    const float* be1    = (const float*)d_in[15];
    const float* We2    = (const float*)d_in[16];
    const float* be2    = (const float*)d_in[17];
    const float* Ws_qkv = (const float*)d_in[18];
    const float* bs_qkv = (const float*)d_in[19];
    const float* Ws_o   = (const float*)d_in[20];
    const float* bs_o   = (const float*)d_in[21];

    float* out_att    = (float*)d_out;               // 4*256*512
    float* out_sparse = out_att + 4 * 256 * 512;     // 4*256*256

    // workspace layout (floats)
    float* ws    = (float*)d_ws;
    float* qkvb  = ws;                    // 1,572,864 (also y-buffer for fuse3)
    float* attnb = qkvb + 1572864;        //   524,288
    float* lvls  = attnb + 524288;        //   917,504 (lvl0 | lvl1 | lvl2)
    float* poolb = lvls + 917504;         //   131,072
    float* curb  = poolb + 131072;        //   262,144
    float* hier  = curb + 262144;         //   524,288
    float* hib   = hier + 524288;         //   524,288  [1024][512]
    float* hjT   = hib + 524288;          //   524,288  [512][1024]
    float* scb   = hjT + 524288;          //   262,144

    float* lvl0 = lvls;
    float* lvl1 = lvls + 1024 * 512;
    float* lvl2 = lvls + 1536 * 512;

    auto G64 = [&](const float* A, const float* W, const float* bias, float* C,
                   int M, int N, int K, int flags, int wmode) {
        gemm_v3<64, float><<<dim3(N / 64, M / 64), 256, 0, stream>>>(
            A, W, bias, C, M, N, K, flags, wmode);
    };
    auto G32 = [&](const float* A, const float* W, const float* bias, float* C,
                   int M, int N, int K, int flags, int wmode) {
        gemm_v3<32, float><<<dim3(N / 64, M / 32), 256, 0, stream>>>(
            A, W, bias, C, M, N, K, flags, wmode);
    };
    auto G64d = [&](const float* A, const float* W, const float* bias, float* C,
                    int M, int N, int K, int flags, int wmode) {
        gemm_v3<64, double><<<dim3(N / 64, M / 64), 256, 0, stream>>>(
            A, W, bias, C, M, N, K, flags, wmode);
    };

    // ---- Level 0 (n=256) ----
    G64(x, Wqkv, bqkv, qkvb, 1024, 1536, 512, 0, 0);
    attn_fused<<<dim3(64, 8, 4), 256, 0, stream>>>(qkvb, attnb, 256);
    G64(attnb, Wo, bo, lvl0, 1024, 512, 512, 0, 0);
    G32(lvl0, Wp1, bp1, poolb, 1024, 256, 512, 3, 0);     // relu+pool -> [512][256]
    G32(poolb, Wp2, bp2, curb, 512, 512, 256, 0, 0);

    // ---- Level 1 (n=128) ----
    G32(curb, Wqkv + 512 * 1536, bqkv + 1536, qkvb, 512, 1536, 512, 0, 0);
    attn_fused<<<dim3(32, 8, 4), 256, 0, stream>>>(qkvb, attnb, 128);
    G32(attnb, Wo + 512 * 512, bo + 512, lvl1, 512, 512, 512, 0, 0);
    G32(lvl1, Wp1 + 512 * 256, bp1 + 256, poolb, 512, 256, 512, 3, 0);  // -> [256][256]
    G32(poolb, Wp2 + 256 * 512, bp2 + 512, curb, 256, 512, 256, 0, 0);

    // ---- Level 2 (n=64) ----
    G32(curb, Wqkv + 2 * 512 * 1536, bqkv + 2 * 1536, qkvb, 256, 1536, 512, 0, 0);
    attn_fused<<<dim3(16, 8, 4), 256, 0, stream>>>(qkvb, attnb, 64);
    G32(attnb, Wo + 2 * 512 * 512, bo + 2 * 512, lvl2, 256, 512, 512, 0, 0);

    // ---- Fuse (batched partial GEMM, f64) + LN ----
    G64d(lvls, Wfuse, nullptr, qkvb, 1792, 512, 512, 0, 1);   // y -> qkvb
    ln3_kernel<<<1024, 64, 0, stream>>>(qkvb, bfuse, ln_g, ln_b, hier);

    // ---- Sparse edge scoring + top-k (f64 near the decision) ----
    G64d(hier, We1, nullptr, hib, 1024, 512, 512, 0, 0);              // hi
    G64d(hier, We1 + 512 * 512, be1, hjT, 1024, 512, 512, 4, 0);      // hj^T
    scores_v2<<<dim3(64, 4), 256, 0, stream>>>(hib, hjT, We2, be2, scb);
    topk_kernel<<<1024, 64, 0, stream>>>(scb, out_sparse);

    // ---- Final MHA on hier (feeds only output 0, tol 2e-2) ----
    G64(hier, Ws_qkv, bs_qkv, qkvb, 1024, 1536, 512, 0, 0);
    attn_fused<<<dim3(64, 8, 4), 256, 0, stream>>>(qkvb, attnb, 256);
    G64(attnb, Ws_o, bs_o, out_att, 1024, 512, 512, 0, 0);
}

// Round 5
// 492.940 us; speedup vs baseline: 3.0680x; 1.1134x over previous
//
#include <hip/hip_runtime.h>
#include <math.h>

// Problem constants: B=4, N=256, D=512, H=8, HD=64, L=3, K_SPARSE=25, EPS=1e-5

// ---------------------------------------------------------------------------
// GEMM v3: C[M,N] = act(A[M,K] @ W[K,N] + bias). Thread owns RT=TM/16
// consecutive rows x 4 consecutive cols -> vectorized LDS fragment reads.
// flags: 1 = relu, 2 = pool (pair-average rows, C gets M/2 rows)
// wmode: 0 none; 1 = fuse3 (W += seg(bm)*512*512, seg rows at 1024/1536);
//        2 = we1-split (W stride 512; bn>=512 -> W += 512*512, bias on; else no bias)
// ---------------------------------------------------------------------------
template <int TM, typename ACC>
__global__ __launch_bounds__(256) void gemm_v3(
    const float* __restrict__ A, const float* __restrict__ W,
    const float* __restrict__ bias, float* __restrict__ C,
    int M, int N, int K, int flags, int wmode)
{
    constexpr int RT = TM / 16;
    constexpr int PAD = (sizeof(ACC) == 4) ? 4 : 2;
    __shared__ ACC As[16][TM + PAD];
    __shared__ ACC Ws[16][64 + PAD];

    const int tid = threadIdx.x;
    const int tx = tid & 15, ty = tid >> 4;
    const int bm = blockIdx.y * TM, bn = blockIdx.x * 64;

    const float* Wp = W;
    const float* bp = bias;
    int wn = N, wcol = bn;
    if (wmode == 1) {
        int seg = (bm >= 1536) ? 2 : (bm >= 1024) ? 1 : 0;
        Wp += (size_t)seg * 262144;
    } else if (wmode == 2) {
        if (bn >= 512) Wp += 262144; else bp = nullptr;
        wn = 512; wcol = bn & 511;
    }

    constexpr int AV = (TM == 64) ? 4 : 2;
    const int ar = (TM == 64) ? (tid >> 2) : (tid >> 3);
    const int ac = (TM == 64) ? ((tid & 3) << 2) : ((tid & 7) << 1);
    const int wr = tid >> 4;
    const int wc = (tid & 15) << 2;

    const float* Aptr = A + (size_t)(bm + ar) * K + ac;
    const float* Wptr = Wp + (size_t)wr * wn + wcol + wc;

    ACC acc[RT][4] = {};
    float ra[AV], rw[4];

    {   // initial prefetch (k0 = 0)
        if (TM == 64) { float4 v = *(const float4*)Aptr;
            ra[0]=v.x; ra[1]=v.y; ra[2]=v.z; ra[3]=v.w; }
        else { float2 v = *(const float2*)Aptr; ra[0]=v.x; ra[1]=v.y; }
        float4 w = *(const float4*)Wptr;
        rw[0]=w.x; rw[1]=w.y; rw[2]=w.z; rw[3]=w.w;
    }

    for (int k0 = 0; k0 < K; k0 += 16) {
        if (k0) __syncthreads();
        #pragma unroll
        for (int u = 0; u < AV; ++u) As[ac + u][ar] = (ACC)ra[u];
        #pragma unroll
        for (int u = 0; u < 4; ++u) Ws[wr][wc + u] = (ACC)rw[u];
        __syncthreads();

        if (k0 + 16 < K) {
            const float* ap = Aptr + k0 + 16;
            if (TM == 64) { float4 v = *(const float4*)ap;
                ra[0]=v.x; ra[1]=v.y; ra[2]=v.z; ra[3]=v.w; }
            else { float2 v = *(const float2*)ap; ra[0]=v.x; ra[1]=v.y; }
            float4 w = *(const float4*)(Wptr + (size_t)(k0 + 16) * wn);
            rw[0]=w.x; rw[1]=w.y; rw[2]=w.z; rw[3]=w.w;
        }

        #pragma unroll
        for (int kk = 0; kk < 16; ++kk) {
            ACC a[RT], w[4];
            #pragma unroll
            for (int i = 0; i < RT; ++i) a[i] = As[kk][ty * RT + i];
            #pragma unroll
            for (int j = 0; j < 4; ++j) w[j] = Ws[kk][tx * 4 + j];
            #pragma unroll
            for (int i = 0; i < RT; ++i)
                #pragma unroll
                for (int j = 0; j < 4; ++j)
                    acc[i][j] += a[i] * w[j];
        }
    }

    // epilogue
    #pragma unroll
    for (int j = 0; j < 4; ++j) {
        const int cn = bn + tx * 4 + j;
        const ACC bv = bp ? (ACC)bp[(wmode == 2) ? (cn & 511) : cn] : (ACC)0;
        if (flags & 2) {   // pool: pair-average activated rows
            #pragma unroll
            for (int pi = 0; pi < RT / 2; ++pi) {
                ACC f0 = acc[2 * pi][j] + bv;
                ACC f1 = acc[2 * pi + 1][j] + bv;
                if (flags & 1) {
                    f0 = f0 > (ACC)0 ? f0 : (ACC)0;
                    f1 = f1 > (ACC)0 ? f1 : (ACC)0;
                }
                int prow = ((bm + ty * RT) >> 1) + pi;
                C[(size_t)prow * N + cn] = (float)((f0 + f1) * (ACC)0.5);
            }
        } else {
            #pragma unroll
            for (int i = 0; i < RT; ++i) {
                ACC f = acc[i][j] + bv;
                if (flags & 1) f = f > (ACC)0 ? f : (ACC)0;
                C[(size_t)(bm + ty * RT + i) * N + cn] = (float)f;
            }
        }
    }
}

// ---------------------------------------------------------------------------
// Fused MHA core: out[b,i,h*64+d] = softmax(QK^T * 0.125) V
// qkv layout [B][n][1536] (q | k | v). Block = (4 q-rows, h, b), 4 waves.
// ---------------------------------------------------------------------------
__global__ __launch_bounds__(256) void attn_fused(
    const float* __restrict__ qkv, float* __restrict__ out, int n)
{
    const int lane = threadIdx.x & 63;
    const int w    = threadIdx.x >> 6;
    const int h = blockIdx.y, b = blockIdx.z;
    const int qi = blockIdx.x * 4 + w;
    const int nt = n >> 6;
    const size_t base = (size_t)b * n * 1536;

    __shared__ float q_lds[4][64];
    __shared__ float kv_lds[64][65];
    __shared__ float p_lds[4][256];

    q_lds[w][lane] = qkv[base + (size_t)qi * 1536 + h * 64 + lane];

    float s[4];
    for (int t = 0; t < nt; ++t) {
        const int j0 = t * 64;
        __syncthreads();
        {
            int r = threadIdx.x >> 2;
            int q4 = threadIdx.x & 3;
            const float* src = qkv + base + (size_t)(j0 + r) * 1536 + 512 + h * 64;
            #pragma unroll
            for (int u = 0; u < 4; ++u) {
                int c = u * 4 + q4;
                float4 v = *(const float4*)(src + c * 4);
                kv_lds[r][c * 4 + 0] = v.x; kv_lds[r][c * 4 + 1] = v.y;
                kv_lds[r][c * 4 + 2] = v.z; kv_lds[r][c * 4 + 3] = v.w;
            }
        }
        __syncthreads();
        float a0 = 0.f, a1 = 0.f, a2 = 0.f, a3 = 0.f;
        #pragma unroll
        for (int d = 0; d < 64; d += 4) {
            a0 += q_lds[w][d + 0] * kv_lds[lane][d + 0];
            a1 += q_lds[w][d + 1] * kv_lds[lane][d + 1];
            a2 += q_lds[w][d + 2] * kv_lds[lane][d + 2];
            a3 += q_lds[w][d + 3] * kv_lds[lane][d + 3];
        }
        s[t] = ((a0 + a1) + (a2 + a3)) * 0.125f;
    }

    float m = s[0];
    for (int t = 1; t < nt; ++t) m = fmaxf(m, s[t]);
    #pragma unroll
    for (int off = 32; off; off >>= 1) m = fmaxf(m, __shfl_xor(m, off));
    float p[4];
    double sum = 0.0;
    for (int t = 0; t < nt; ++t) { p[t] = expf(s[t] - m); sum += (double)p[t]; }
    #pragma unroll
    for (int off = 32; off; off >>= 1) sum += __shfl_xor(sum, off);
    const double inv = 1.0 / sum;
    for (int t = 0; t < nt; ++t) p_lds[w][t * 64 + lane] = p[t];

    float ac0 = 0.f, ac1 = 0.f, ac2 = 0.f, ac3 = 0.f;
    for (int t = 0; t < nt; ++t) {
        const int j0 = t * 64;
        __syncthreads();
        {
            int r = threadIdx.x >> 2;
            int q4 = threadIdx.x & 3;
            const float* src = qkv + base + (size_t)(j0 + r) * 1536 + 1024 + h * 64;
            #pragma unroll
            for (int u = 0; u < 4; ++u) {
                int c = u * 4 + q4;
                float4 v = *(const float4*)(src + c * 4);
                kv_lds[r][c * 4 + 0] = v.x; kv_lds[r][c * 4 + 1] = v.y;
                kv_lds[r][c * 4 + 2] = v.z; kv_lds[r][c * 4 + 3] = v.w;
            }
        }
        __syncthreads();
        #pragma unroll
        for (int jl = 0; jl < 64; jl += 4) {
            ac0 = fmaf(p_lds[w][j0 + jl + 0], kv_lds[jl + 0][lane], ac0);
            ac1 = fmaf(p_lds[w][j0 + jl + 1], kv_lds[jl + 1][lane], ac1);
            ac2 = fmaf(p_lds[w][j0 + jl + 2], kv_lds[jl + 2][lane], ac2);
            ac3 = fmaf(p_lds[w][j0 + jl + 3], kv_lds[jl + 3][lane], ac3);
        }
    }
    float acc = (ac0 + ac1) + (ac2 + ac3);
    out[((size_t)(b * n + qi)) * 512 + h * 64 + lane] = (float)((double)acc * inv);
}

// ---------------------------------------------------------------------------
// Fused 3-way add + bias + relu + LayerNorm. y = [y0(1024r) | y1(512r) | y2(256r)]
// ---------------------------------------------------------------------------
__global__ __launch_bounds__(64) void ln3_kernel(
    const float* __restrict__ y, const float* __restrict__ bf,
    const float* __restrict__ g, const float* __restrict__ bta,
    float* __restrict__ out)
{
    const int r = blockIdx.x, lane = threadIdx.x;
    const int b = r >> 8, i = r & 255;
    const float* y0 = y + (size_t)r * 512;
    const float* y1 = y + (size_t)(1024 + b * 128 + (i >> 1)) * 512;
    const float* y2 = y + (size_t)(1536 + b * 64 + (i >> 2)) * 512;
    double v[8];
    double sum = 0.0;
    #pragma unroll
    for (int t = 0; t < 8; ++t) {
        int d = t * 64 + lane;
        double s = (double)y0[d] + (double)y1[d] + (double)y2[d] + (double)bf[d];
        s = s > 0.0 ? s : 0.0;
        v[t] = s; sum += s;
    }
    #pragma unroll
    for (int off = 32; off; off >>= 1) sum += __shfl_xor(sum, off);
    const double mean = sum * (1.0 / 512.0);
    double ss = 0.0;
    #pragma unroll
    for (int t = 0; t < 8; ++t) { double d = v[t] - mean; ss += d * d; }
    #pragma unroll
    for (int off = 32; off; off >>= 1) ss += __shfl_xor(ss, off);
    const double rstd = 1.0 / sqrt(ss * (1.0 / 512.0) + 1e-5);
    #pragma unroll
    for (int t = 0; t < 8; ++t) {
        int d = t * 64 + lane;
        out[(size_t)r * 512 + d] =
            (float)((v[t] - mean) * rstd * (double)g[d] + (double)bta[d]);
    }
}

// ---------------------------------------------------------------------------
// Edge scores v3 (GEMM-shaped): z[i,j] = sum_d relu(hi[i,d]+hj[j,d]) * w2[d]
// S = sigmoid(z + be2), diag 0. hibjb[1024][1024]: cols 0:512 hi, 512:1024 hj.
// Block = 32x32 (i,j) tile, 256 threads, thread owns 2x2, f64 accumulation.
// grid: (8 jt, 8 it, 4 b).
// ---------------------------------------------------------------------------
__global__ __launch_bounds__(256) void scores_v3(
    const float* __restrict__ hibjb, const float* __restrict__ We2,
    const float* __restrict__ be2, float* __restrict__ S)
{
    __shared__ float Hi[16][36];   // [d][i], padded
    __shared__ float Hj[16][36];   // [d][j], padded
    __shared__ float W2s[512];
    const int b = blockIdx.z;
    const int i0 = blockIdx.y * 32, j0 = blockIdx.x * 32;
    const int tid = threadIdx.x;
    const int tx = tid & 15, ty = tid >> 4;   // j-group, i-group

    for (int t = tid; t < 512; t += 256) W2s[t] = We2[t];

    // staging map: thread -> row sr (0..31), col pair sc (0,2,..,14)
    const int sr = tid >> 3, sc = (tid & 7) << 1;
    const float* hiptr = hibjb + (size_t)(b * 256 + i0 + sr) * 1024 + sc;
    const float* hjptr = hibjb + (size_t)(b * 256 + j0 + sr) * 1024 + 512 + sc;

    double a00 = 0.0, a01 = 0.0, a10 = 0.0, a11 = 0.0;
    for (int k0 = 0; k0 < 512; k0 += 16) {
        __syncthreads();
        float2 hv = *(const float2*)(hiptr + k0);
        float2 jv = *(const float2*)(hjptr + k0);
        Hi[sc + 0][sr] = hv.x; Hi[sc + 1][sr] = hv.y;
        Hj[sc + 0][sr] = jv.x; Hj[sc + 1][sr] = jv.y;
        __syncthreads();
        #pragma unroll
        for (int kk = 0; kk < 16; ++kk) {
            const double wv = (double)W2s[k0 + kk];
            const float hi0 = Hi[kk][ty * 2 + 0], hi1 = Hi[kk][ty * 2 + 1];
            const float hj0 = Hj[kk][tx * 2 + 0], hj1 = Hj[kk][tx * 2 + 1];
            a00 += (double)fmaxf(hi0 + hj0, 0.f) * wv;
            a01 += (double)fmaxf(hi0 + hj1, 0.f) * wv;
            a10 += (double)fmaxf(hi1 + hj0, 0.f) * wv;
            a11 += (double)fmaxf(hi1 + hj1, 0.f) * wv;
        }
    }
    const double bb = (double)be2[0];
    const int gi0 = i0 + ty * 2, gj0 = j0 + tx * 2;
    double zz[2][2] = {{a00, a01}, {a10, a11}};
    #pragma unroll
    for (int ii = 0; ii < 2; ++ii)
        #pragma unroll
        for (int jj = 0; jj < 2; ++jj) {
            double z = zz[ii][jj] + bb;
            float sc_ = (float)(1.0 / (1.0 + exp(-z)));
            if (gi0 + ii == gj0 + jj) sc_ = 0.f;
            S[(size_t)(b * 256 + gi0 + ii) * 256 + gj0 + jj] = sc_;
        }
}

// ---------------------------------------------------------------------------
// Top-k(25) one-hot per row of 256 (ties -> lower index, like lax.top_k).
// ---------------------------------------------------------------------------
__global__ __launch_bounds__(64) void topk_kernel(
    const float* __restrict__ S, float* __restrict__ out)
{
    const int row = blockIdx.x;
    const int lane = threadIdx.x;
    float v[4]; int sel[4] = {0, 0, 0, 0};
    #pragma unroll
    for (int t = 0; t < 4; ++t) v[t] = S[(size_t)row * 256 + t * 64 + lane];
    for (int it = 0; it < 25; ++it) {
        float bv = v[0]; int bi = lane;
        #pragma unroll
        for (int t = 1; t < 4; ++t) {
            int idx = t * 64 + lane;
            if (v[t] > bv) { bv = v[t]; bi = idx; }
        }
        #pragma unroll
        for (int off = 32; off; off >>= 1) {
            float ov = __shfl_xor(bv, off);
            int   oi = __shfl_xor(bi, off);
            if (ov > bv || (ov == bv && oi < bi)) { bv = ov; bi = oi; }
        }
        if ((bi & 63) == lane) { int t = bi >> 6; sel[t] = 1; v[t] = -INFINITY; }
    }
    #pragma unroll
    for (int t = 0; t < 4; ++t)
        out[(size_t)row * 256 + t * 64 + lane] = (float)sel[t];
}

// ---------------------------------------------------------------------------
extern "C" void kernel_launch(void* const* d_in, const int* in_sizes, int n_in,
                              void* d_out, int out_size, void* d_ws, size_t ws_size,
                              hipStream_t stream)
{
    const float* x      = (const float*)d_in[0];
    const float* Wqkv   = (const float*)d_in[2];
    const float* bqkv   = (const float*)d_in[3];
    const float* Wo     = (const float*)d_in[4];
    const float* bo     = (const float*)d_in[5];
    const float* Wp1    = (const float*)d_in[6];
    const float* bp1    = (const float*)d_in[7];
    const float* Wp2    = (const float*)d_in[8];
    const float* bp2    = (const float*)d_in[9];
    const float* Wfuse  = (const float*)d_in[10];
    const float* bfuse  = (const float*)d_in[11];
    const float* ln_g   = (const float*)d_in[12];
    const float* ln_b   = (const float*)d_in[13];
    const float* We1    = (const float*)d_in[14];
    const float* be1    = (const float*)d_in[15];
    const float* We2    = (const float*)d_in[16];
    const float* be2    = (const float*)d_in[17];
    const float* Ws_qkv = (const float*)d_in[18];
    const float* bs_qkv = (const float*)d_in[19];
    const float* Ws_o   = (const float*)d_in[20];
    const float* bs_o   = (const float*)d_in[21];

    float* out_att    = (float*)d_out;               // 4*256*512
    float* out_sparse = out_att + 4 * 256 * 512;     // 4*256*256

    // workspace layout (floats), total ~5.24M fl = 21 MB
    float* ws    = (float*)d_ws;
    float* qkvb  = ws;                    // 1,572,864 (also y-buffer for fuse3)
    float* attnb = qkvb + 1572864;        //   524,288
    float* lvls  = attnb + 524288;        //   917,504 (lvl0 | lvl1 | lvl2)
    float* poolb = lvls + 917504;         //   131,072
    float* curb  = poolb + 131072;        //   262,144
    float* hier  = curb + 262144;         //   524,288
    float* hibjb = hier + 524288;         // 1,048,576  [1024][1024] (hi | hj)
    float* scb   = hibjb + 1048576;       //   262,144

    float* lvl0 = lvls;
    float* lvl1 = lvls + 1024 * 512;
    float* lvl2 = lvls + 1536 * 512;

    auto G64 = [&](const float* A, const float* W, const float* bias, float* C,
                   int M, int N, int K, int flags, int wmode) {
        gemm_v3<64, float><<<dim3(N / 64, M / 64), 256, 0, stream>>>(
            A, W, bias, C, M, N, K, flags, wmode);
    };
    auto G32 = [&](const float* A, const float* W, const float* bias, float* C,
                   int M, int N, int K, int flags, int wmode) {
        gemm_v3<32, float><<<dim3(N / 64, M / 32), 256, 0, stream>>>(
            A, W, bias, C, M, N, K, flags, wmode);
    };
    auto G64d = [&](const float* A, const float* W, const float* bias, float* C,
                    int M, int N, int K, int flags, int wmode) {
        gemm_v3<64, double><<<dim3(N / 64, M / 64), 256, 0, stream>>>(
            A, W, bias, C, M, N, K, flags, wmode);
    };

    // ---- Level 0 (n=256) ----
    G64(x, Wqkv, bqkv, qkvb, 1024, 1536, 512, 0, 0);
    attn_fused<<<dim3(64, 8, 4), 256, 0, stream>>>(qkvb, attnb, 256);
    G64(attnb, Wo, bo, lvl0, 1024, 512, 512, 0, 0);
    G32(lvl0, Wp1, bp1, poolb, 1024, 256, 512, 3, 0);     // relu+pool -> [512][256]
    G32(poolb, Wp2, bp2, curb, 512, 512, 256, 0, 0);

    // ---- Level 1 (n=128) ----
    G32(curb, Wqkv + 512 * 1536, bqkv + 1536, qkvb, 512, 1536, 512, 0, 0);
    attn_fused<<<dim3(32, 8, 4), 256, 0, stream>>>(qkvb, attnb, 128);
    G32(attnb, Wo + 512 * 512, bo + 512, lvl1, 512, 512, 512, 0, 0);
    G32(lvl1, Wp1 + 512 * 256, bp1 + 256, poolb, 512, 256, 512, 3, 0);  // -> [256][256]
    G32(poolb, Wp2 + 256 * 512, bp2 + 512, curb, 256, 512, 256, 0, 0);

    // ---- Level 2 (n=64) ----
    G32(curb, Wqkv + 2 * 512 * 1536, bqkv + 2 * 1536, qkvb, 256, 1536, 512, 0, 0);
    attn_fused<<<dim3(16, 8, 4), 256, 0, stream>>>(qkvb, attnb, 64);
    G32(attnb, Wo + 2 * 512 * 512, bo + 2 * 512, lvl2, 256, 512, 512, 0, 0);

    // ---- Fuse (batched partial GEMM, f64) + LN ----
    G64d(lvls, Wfuse, nullptr, qkvb, 1792, 512, 512, 0, 1);   // y -> qkvb
    ln3_kernel<<<1024, 64, 0, stream>>>(qkvb, bfuse, ln_g, ln_b, hier);

    // ---- Sparse edge scoring + top-k (f64 near the decision) ----
    G64d(hier, We1, be1, hibjb, 1024, 1024, 512, 0, 2);       // [hi | hj]
    scores_v3<<<dim3(8, 8, 4), 256, 0, stream>>>(hibjb, We2, be2, scb);
    topk_kernel<<<1024, 64, 0, stream>>>(scb, out_sparse);

    // ---- Final MHA on hier (feeds only output 0, tol 2e-2) ----
    G64(hier, Ws_qkv, bs_qkv, qkvb, 1024, 1536, 512, 0, 0);
    attn_fused<<<dim3(64, 8, 4), 256, 0, stream>>>(qkvb, attnb, 256);
    G64(attnb, Ws_o, bs_o, out_att, 1024, 512, 512, 0, 0);
}